// Round 9
// baseline (571.554 us; speedup 1.0000x reference)
//
#include <hip/hip_runtime.h>

#define HIDDEN 51
#define LSEQ 1000
#define UNROLL 8    // steps buffered between butterfly/store groups

// Branch-free tanh: tanh(v) = 1 - 2/(exp2(2*log2e*v)+1). Saturates to +/-1.
__device__ __forceinline__ float fast_tanh(float v) {
    float e = __builtin_amdgcn_exp2f(v * 2.885390081777927f);  // 2*log2(e)
    float r = __builtin_amdgcn_rcpf(e + 1.0f);
    return fmaf(-2.0f, r, 1.0f);
}

// One wave per batch element, no block barriers. Evidence so far:
//  - h broadcast via LDS same-address reads (hk -> VGPR) is the only clean
//    broadcast: readlane->SGPR forces v_accvgpr_read per AGPR-resident U
//    element (R5/R7, ~40% issue tax); LDS hk + scalar VOP3 fma sources AGPRs
//    directly (R4, zero tax).
//  - v_pk_fma_f32 is half-rate on CDNA4 fp32 (157 TF peak has no packed
//    doubling) -> same issue cost as scalar, plus possible VOP3P/AGPR copy
//    tax. R9 reverts to scalar fmaf.
//  - R8's 722 stall cyc/step = 13 ds_read latencies partially exposed
//    (reads interleaved with FMAs). R9 hoists ALL 13 float4 h-loads ahead
//    of the FMA block: one exposed LDS round-trip (~120 cyc), the rest
//    drains under the 416-cycle FMA issue stream.
//  - Output projection stays hoisted: 8 steps of h*lw buffered in registers,
//    then 8 independent butterflies + one lane0 float4 x2 store per group.
__global__ __launch_bounds__(64, 1) void lstm_seq_kernel(
    const float* __restrict__ x,
    const float* __restrict__ W_w,
    const float* __restrict__ W_b,
    const float* __restrict__ U_w,
    const float* __restrict__ U_b,
    const float* __restrict__ lin_w,
    const float* __restrict__ lin_b,
    float* __restrict__ out)
{
    __shared__ __attribute__((aligned(16))) float hb[64];  // h broadcast

    const int b    = blockIdx.x;
    const int lane = threadIdx.x;        // 0..63
    const bool active = lane < HIDDEN;   // lanes 51..63 produce exact zeros
    const int m = active ? lane : 0;

    float ww[4], bb[4];
#pragma unroll
    for (int g = 0; g < 4; ++g) {
        const int row = m + g * HIDDEN;
        ww[g] = active ? W_w[row] : 0.f;
        bb[g] = active ? (W_b[row] + U_b[row]) : 0.f;
    }
    const float lw = active ? lin_w[m] : 0.f;
    const float lb = lin_b[0];

    // U[g][k]: this lane's 4 gate rows. 204 floats -> AGPRs (fine for VOP3).
    // k index padded to 52 so the hv-word mapping is uniform; col 51 = 0
    // (matches hb[51] == 0 from lane 51's h == 0).
    float U[4][52];
#pragma unroll
    for (int g = 0; g < 4; ++g) {
        const int row = m + g * HIDDEN;
#pragma unroll
        for (int k = 0; k < 52; ++k)
            U[g][k] = (active && k < HIDDEN) ? U_w[row * HIDDEN + k] : 0.f;
    }

    float h = 0.f, c = 0.f;
    const float* __restrict__ xrow = x + (long)b * LSEQ;
    float* __restrict__ orow = out + (long)b * LSEQ;

    hb[lane] = 0.f;                       // single wave: in-order LDS pipe
    __builtin_amdgcn_wave_barrier();      // ordering insurance (no-op inst)

    for (int T = 0; T < LSEQ; T += UNROLL) {
        float xg[UNROLL], rb[UNROLL];
#pragma unroll
        for (int s = 0; s < UNROLL; ++s) xg[s] = xrow[T + s];  // uniform

#pragma unroll
        for (int s = 0; s < UNROLL; ++s) {
            // ---- hoist ALL h broadcasts first: 13 x ds_read_b128, ----
            // ---- same-address broadcast, conflict-free, -> VGPRs.   ----
            float4 hv[13];
#pragma unroll
            for (int q = 0; q < 13; ++q)
                hv[q] = *(const float4*)&hb[q * 4];

            // ---- 4 x 52-deep FMA chains (scalar VOP3; AGPR U ok). ----
            float gi = fmaf(xg[s], ww[0], bb[0]);
            float gf = fmaf(xg[s], ww[1], bb[1]);
            float gg = fmaf(xg[s], ww[2], bb[2]);
            float go = fmaf(xg[s], ww[3], bb[3]);
#pragma unroll
            for (int q = 0; q < 13; ++q) {
                const float h0 = hv[q].x, h1 = hv[q].y;
                const float h2 = hv[q].z, h3 = hv[q].w;
                const int k = q * 4;
                gi = fmaf(h0, U[0][k],     gi);
                gf = fmaf(h0, U[1][k],     gf);
                gg = fmaf(h0, U[2][k],     gg);
                go = fmaf(h0, U[3][k],     go);
                gi = fmaf(h1, U[0][k + 1], gi);
                gf = fmaf(h1, U[1][k + 1], gf);
                gg = fmaf(h1, U[2][k + 1], gg);
                go = fmaf(h1, U[3][k + 1], go);
                gi = fmaf(h2, U[0][k + 2], gi);
                gf = fmaf(h2, U[1][k + 2], gf);
                gg = fmaf(h2, U[2][k + 2], gg);
                go = fmaf(h2, U[3][k + 2], go);
                gi = fmaf(h3, U[0][k + 3], gi);
                gf = fmaf(h3, U[1][k + 3], gf);
                gg = fmaf(h3, U[2][k + 3], gg);
                go = fmaf(h3, U[3][k + 3], go);
            }

            // NOTE: faithful to reference -- no sigmoid on gates.
            c = fmaf(gf, c, gi * gg);
            h = go * fast_tanh(c);        // inactive lanes stay exactly 0
            rb[s] = h * lw;

            __builtin_amdgcn_wave_barrier();  // reads above precede write
            hb[lane] = h;
            __builtin_amdgcn_wave_barrier();  // write precedes next reads
        }

        // 8 independent butterflies -- swizzle latencies overlap across s.
#pragma unroll
        for (int s = 0; s < UNROLL; ++s) {
#pragma unroll
            for (int off = 32; off > 0; off >>= 1)
                rb[s] += __shfl_xor(rb[s], off, 64);
        }
        if (lane == 0) {
            float4 o0 = {rb[0] + lb, rb[1] + lb, rb[2] + lb, rb[3] + lb};
            float4 o1 = {rb[4] + lb, rb[5] + lb, rb[6] + lb, rb[7] + lb};
            *(float4*)&orow[T]     = o0;   // orow 16B-aligned (b*4000 bytes)
            *(float4*)&orow[T + 4] = o1;
        }
    }
}

extern "C" void kernel_launch(void* const* d_in, const int* in_sizes, int n_in,
                              void* d_out, int out_size, void* d_ws, size_t ws_size,
                              hipStream_t stream) {
    const float* x     = (const float*)d_in[0];
    const float* W_w   = (const float*)d_in[1];
    const float* W_b   = (const float*)d_in[2];
    const float* U_w   = (const float*)d_in[3];
    const float* U_b   = (const float*)d_in[4];
    const float* lin_w = (const float*)d_in[5];
    const float* lin_b = (const float*)d_in[6];
    // d_in[7] = future (static 0; out_size == B*LSEQ)
    float* out = (float*)d_out;

    const int B = in_sizes[0] / LSEQ;  // 1024
    lstm_seq_kernel<<<dim3(B), dim3(64), 0, stream>>>(
        x, W_w, W_b, U_w, U_b, lin_w, lin_b, out);
}